// Round 7
// baseline (698.653 us; speedup 1.0000x reference)
//
#include <hip/hip_runtime.h>

#define B 8
#define C 64
#define N 4096
#define O 64
#define KNN 20
#define CAP 8
#define SSTR 68          /* score-row stride: 2-way bank aliasing only (free) */
#define BN_EPS 1e-5f
#define NEG_SLOPE 0.2f

typedef _Float16 f16x8 __attribute__((ext_vector_type(8)));
typedef float    f32x4 __attribute__((ext_vector_type(4)));
#define MFMA16(a, b, c) __builtin_amdgcn_mfma_f32_16x16x32_f16(a, b, c, 0, 0, 0)

__device__ __forceinline__ void gld16(const float* g, float* l) {
    __builtin_amdgcn_global_load_lds((const __attribute__((address_space(1))) void*)g,
                                     (__attribute__((address_space(3))) void*)l, 16, 0, 0);
}

// insert (r,m) into ascending-sorted top-KNN list, dropping old min d[0].
// precondition: r > d[0]. Tie-safe (multiset semantics).
__device__ __forceinline__ void sorted_insert(float (&d)[KNN], int (&id)[KNN],
                                              float r, int m) {
    bool cp = true;
    #pragma unroll
    for (int j = 0; j < KNN - 1; ++j) {
        bool c = d[j + 1] < r;
        float nv = c ? d[j + 1] : (cp ? r : d[j]);
        int   ni = c ? id[j + 1] : (cp ? m : id[j]);
        d[j] = nv; id[j] = ni;
        cp = c;
    }
    d[KNN - 1]  = cp ? r : d[KNN - 1];
    id[KNN - 1] = cp ? m : id[KNN - 1];
}

// drain per-lane LDS survivor stacks; all 64 lanes insert in parallel.
__device__ __forceinline__ void drain(float* svw, int lane, int& cnt,
                                      float (&d)[KNN], int (&id)[KNN]) {
    #pragma unroll 1
    for (int s2 = 0; s2 < CAP; ++s2) {
        if (!__any(s2 < cnt)) break;
        if (s2 < cnt) {
            float2 e = *(const float2*)(svw + s2 * 128 + lane * 2);
            if (e.x > d[0]) sorted_insert(d, id, e.x, __float_as_int(e.y));
        }
    }
    cnt = 0;
}

// -------- K0: x (B,C,N) -> Xt (B,N,C) fp32, sq = ||x_n||^2, and AHL: f16 hi/lo
// frag-major: per 16-row group (4096 B): [term][khalf][quad][slot16][8 f16]
__global__ __launch_bounds__(256) void k_transpose(const float* __restrict__ x,
                                                   float* __restrict__ Xt,
                                                   float* __restrict__ sq,
                                                   char* __restrict__ AHL) {
    __shared__ float lds[C][65];
    int b    = blockIdx.x >> 6;
    int n0   = (blockIdx.x & 63) << 6;
    int lane = threadIdx.x & 63;
    int w    = threadIdx.x >> 6;
    #pragma unroll
    for (int i = 0; i < 16; ++i) {
        int c = w * 16 + i;
        lds[c][lane] = x[(size_t)b * C * N + (size_t)c * N + n0 + lane];
    }
    __syncthreads();
    #pragma unroll
    for (int i = 0; i < 16; ++i) {
        int nl = w * 16 + i;
        float v = lds[lane][nl];
        Xt[(size_t)b * N * C + (size_t)(n0 + nl) * C + lane] = v;
        float s = v * v;
        #pragma unroll
        for (int off = 32; off; off >>= 1) s += __shfl_xor(s, off, 64);
        if (lane == 0) sq[b * N + n0 + nl] = s;
    }
    int s2  = threadIdx.x & 15;
    int rem = threadIdx.x >> 4;
    int qd  = rem & 3;
    int hh  = (rem >> 2) & 1;
    int tt  = rem >> 3;
    int kb  = hh * 32 + qd * 8;
    for (int i = 0; i < 4; ++i) {
        int rowl = i * 16 + s2;
        f16x8 pk;
        #pragma unroll
        for (int ii = 0; ii < 8; ++ii) {
            float v = lds[kb + ii][rowl];
            _Float16 hv = (_Float16)v;
            if (tt) hv = (_Float16)(v - (float)hv);
            pk[ii] = hv;
        }
        char* dst = AHL + ((size_t)b << 20) + (size_t)((n0 >> 4) + i) * 4096
                  + tt * 2048 + hh * 1024 + qd * 256 + s2 * 16;
        *(f16x8*)dst = pk;
    }
}

// -------- K1: a = X*(W1-W2)^T, bvec = X*W2^T
__global__ __launch_bounds__(256, 2) void k_ab(const float* __restrict__ Xt,
                                               const float* __restrict__ W,
                                               float* __restrict__ av,
                                               float* __restrict__ bv) {
    int b  = blockIdx.x >> 5;
    int n0 = (blockIdx.x & 31) << 7;
    int o  = threadIdx.x & 63;
    int w  = __builtin_amdgcn_readfirstlane((int)(threadIdx.x >> 6));
    float wa[C], wb[C];
    #pragma unroll
    for (int c = 0; c < C; ++c) {
        float w1 = W[o * 2 * C + c];
        float w2 = W[o * 2 * C + C + c];
        wa[c] = w1 - w2;
        wb[c] = w2;
    }
    const float* xb = Xt + (size_t)b * N * C;
    for (int i = 0; i < 32; ++i) {
        int n = n0 + w * 32 + i;
        const float* xr = xb + (size_t)n * C;
        float aa = 0.f, bb = 0.f;
        #pragma unroll
        for (int c = 0; c < C; ++c) {
            float xc = xr[c];
            aa = fmaf(xc, wa[c], aa);
            bb = fmaf(xc, wb[c], bb);
        }
        size_t oidx = ((size_t)b * N + n) * O + o;
        av[oidx] = aa;
        bv[oidx] = bb;
    }
}

// -------- K2: MFMA distance tiles + survivor-stack top-20 (sorted_insert drains)
// block: 64 query rows (rb). wave w owns cand-group w of each 64-cand tile;
// B-frags for all 4 query groups pinned in regs. scan: lane = query row.
__global__ __launch_bounds__(256, 3) void k_knn(const char* __restrict__ AHL,
                                                const float* __restrict__ sq,
                                                int* __restrict__ knn) {
    __shared__ __align__(16) char smem[50176];
    char*  cb = smem;                          // 16 KB cand tile
    float* S  = (float*)(smem + 16384);        // 64 x 68 floats = 17408 B
    float* sv = (float*)(smem + 33792);        // surv [w][slot][lane] f2 = 16 KB

    int b    = blockIdx.x >> 6;
    int rb   = blockIdx.x & 63;
    int n0   = rb << 6;
    int tid  = threadIdx.x;
    int lane = tid & 63;
    int w    = __builtin_amdgcn_readfirstlane(tid >> 6);
    const char*  AHLb = AHL + ((size_t)b << 20);
    const float* sqb  = sq + b * N;
    float* svw = sv + w * 1024;

    // B-frags: all 4 query groups, hi/lo x khalf (64 VGPRs, once per block)
    f16x8 bh[4][2], bl[4][2];
    #pragma unroll
    for (int g = 0; g < 4; ++g) {
        const char* qb = AHLb + (size_t)(rb * 4 + g) * 4096 + lane * 16;
        bh[g][0] = *(const f16x8*)(qb);
        bh[g][1] = *(const f16x8*)(qb + 1024);
        bl[g][0] = *(const f16x8*)(qb + 2048);
        bl[g][1] = *(const f16x8*)(qb + 3072);
    }

    float d[KNN]; int id[KNN];
    #pragma unroll
    for (int j = 0; j < KNN; ++j) { d[j] = -3.4e38f; id[j] = 0; }
    int cnt = 0;

    // stage tile 0 (wave w stages its own cand-group w: 4 KB)
    #pragma unroll
    for (int j2 = 0; j2 < 4; ++j2) {
        int ch = (w * 4 + j2) * 1024 + lane * 16;
        gld16((const float*)(AHLb + ch), (float*)(cb + ch));
    }
    __syncthreads();

    for (int t = 0; t < 64; ++t) {
        // ---- MFMA phase: wave w computes S[cands w*16..+16][all 64 queries]
        const char* ct = cb + w * 4096 + lane * 16;
        f16x8 ah0 = *(const f16x8*)(ct);
        f16x8 ah1 = *(const f16x8*)(ct + 1024);
        f16x8 al0 = *(const f16x8*)(ct + 2048);
        f16x8 al1 = *(const f16x8*)(ct + 3072);
        float4 sqv = *(const float4*)(sqb + t * 64 + w * 16 + ((lane >> 4) << 2));
        int mr0 = w * 16 + ((lane >> 4) << 2);
        int col = lane & 15;
        #pragma unroll
        for (int g = 0; g < 4; ++g) {
            f32x4 acc = {0.f, 0.f, 0.f, 0.f};
            acc = MFMA16(ah0, bh[g][0], acc);
            acc = MFMA16(ah1, bh[g][1], acc);
            acc = MFMA16(ah0, bl[g][0], acc);
            acc = MFMA16(ah1, bl[g][1], acc);
            acc = MFMA16(al0, bh[g][0], acc);
            acc = MFMA16(al1, bh[g][1], acc);
            S[(mr0 + 0) * SSTR + g * 16 + col] = fmaf(2.f, acc[0], -sqv.x);
            S[(mr0 + 1) * SSTR + g * 16 + col] = fmaf(2.f, acc[1], -sqv.y);
            S[(mr0 + 2) * SSTR + g * 16 + col] = fmaf(2.f, acc[2], -sqv.z);
            S[(mr0 + 3) * SSTR + g * 16 + col] = fmaf(2.f, acc[3], -sqv.w);
        }
        __syncthreads();   // S complete; all cb reads of tile t done

        // ---- stage next tile (async; drained at barrier B) + scan
        if (t + 1 < 64) {
            const char* src = AHLb + (size_t)(t + 1) * 16384;
            #pragma unroll
            for (int j2 = 0; j2 < 4; ++j2) {
                int ch = (w * 4 + j2) * 1024 + lane * 16;
                gld16((const float*)(src + ch), (float*)(cb + ch));
            }
        }
        int cbase = t * 64 + w * 16;
        const float* Srow = S + w * 16 * SSTR + lane;
        #pragma unroll 4
        for (int jj = 0; jj < 16; ++jj) {
            float r = Srow[jj * SSTR];
            if (r > d[0]) {                    // cheap push to per-lane LDS stack
                *(float2*)(svw + cnt * 128 + lane * 2) =
                    make_float2(r, __int_as_float(cbase + jj));
                ++cnt;
            }
            if (__any(cnt == CAP)) drain(svw, lane, cnt, d, id);
        }
        __syncthreads();   // drains async stage; protects cb & S
    }
    drain(svw, lane, cnt, d, id);              // final flush

    // in-block merge of the 4 waves' sorted partial lists
    __syncthreads();
    float* md = (float*)smem;                  // [4][64][20] floats, 20 KB
    int*   mi = (int*)(smem + 20480);          // [4][64][20] ints,  20 KB
    #pragma unroll
    for (int j = 0; j < KNN; ++j) {
        md[(w * 64 + lane) * KNN + j] = d[j];
        mi[(w * 64 + lane) * KNN + j] = id[j];
    }
    __syncthreads();
    if (w == 0) {
        for (int ww = 1; ww < 4; ++ww) {
            const float* lp = md + (ww * 64 + lane) * KNN;
            const int*   lq = mi + (ww * 64 + lane) * KNN;
            for (int j = KNN - 1; j >= 0; --j) {   // descending; early-exit
                float r = lp[j];
                if (!__any(r > d[0])) break;
                if (r > d[0]) sorted_insert(d, id, r, lq[j]);
            }
        }
        int* op = knn + ((size_t)b * N + n0 + lane) * KNN;
        #pragma unroll
        for (int j = 0; j < KNN; ++j) op[j] = id[j];
    }
}

// -------- K3: out[b][o][n] = leaky(scale*(a[n][o] + max_k bvec[idx_k][o]) + bias)
__global__ __launch_bounds__(256) void k_out(const float* __restrict__ av,
                                             const float* __restrict__ bv,
                                             const int* __restrict__ knn,
                                             const float* __restrict__ gamma,
                                             const float* __restrict__ beta,
                                             const float* __restrict__ rmean,
                                             const float* __restrict__ rvar,
                                             float* __restrict__ out) {
    __shared__ float lds[64][65];
    int b    = blockIdx.x >> 6;
    int n0   = (blockIdx.x & 63) << 6;
    int lane = threadIdx.x & 63;
    int w    = __builtin_amdgcn_readfirstlane((int)(threadIdx.x >> 6));
    int o    = lane;
    float scale = gamma[o] * rsqrtf(rvar[o] + BN_EPS);
    float bias  = fmaf(-rmean[o], scale, beta[o]);
    const float* bvb = bv + (size_t)b * N * O;
    for (int i = 0; i < 16; ++i) {
        int n = n0 + w * 16 + i;
        const int* kn = knn + ((size_t)b * N + n) * KNN;
        float mx = -3.4e38f, mn = 3.4e38f;
        #pragma unroll
        for (int j = 0; j < KNN; ++j) {
            float v = bvb[(size_t)kn[j] * O + o];
            mx = fmaxf(mx, v);
            mn = fminf(mn, v);
        }
        float a   = av[((size_t)b * N + n) * O + o];
        float sel = (scale >= 0.f) ? (a + mx) : (a + mn);
        float y   = fmaf(sel, scale, bias);
        y = fmaxf(y, NEG_SLOPE * y);
        lds[o][w * 16 + i] = y;
    }
    __syncthreads();
    int r  = threadIdx.x >> 2;
    int c0 = (threadIdx.x & 3) << 4;
    float* ob = out + (size_t)b * O * N + (size_t)r * N + n0;
    #pragma unroll
    for (int j = 0; j < 16; j += 4) {
        float4 v;
        v.x = lds[r][c0 + j + 0];
        v.y = lds[r][c0 + j + 1];
        v.z = lds[r][c0 + j + 2];
        v.w = lds[r][c0 + j + 3];
        *(float4*)(ob + c0 + j) = v;
    }
}

extern "C" void kernel_launch(void* const* d_in, const int* in_sizes, int n_in,
                              void* d_out, int out_size, void* d_ws, size_t ws_size,
                              hipStream_t stream) {
    const float* x     = (const float*)d_in[0];
    const float* W     = (const float*)d_in[1];
    const float* gamma = (const float*)d_in[2];
    const float* beta  = (const float*)d_in[3];
    const float* rmean = (const float*)d_in[4];
    const float* rvar  = (const float*)d_in[5];
    float* out = (float*)d_out;

    char* wsb = (char*)d_ws;
    float* Xt  = (float*)(wsb);                 //  8 MB
    float* sqn = (float*)(wsb + 8388608);       //  128 KB
    float* av  = (float*)(wsb + 8519680);       //  8 MB
    float* bvv = (float*)(wsb + 16908288);      //  8 MB
    int*   knn = (int*)  (wsb + 25296896);      //  2.5 MB
    char*  AHL =         (wsb + 27918336);      //  8 MB f16 hi/lo frag-major

    k_transpose<<<512, 256, 0, stream>>>(x, Xt, sqn, AHL);
    k_ab<<<256, 256, 0, stream>>>(Xt, W, av, bvv);
    k_knn<<<512, 256, 0, stream>>>(AHL, sqn, knn);
    k_out<<<512, 256, 0, stream>>>(av, bvv, knn, gamma, beta, rmean, rvar, out);
}